// Round 6
// baseline (176.132 us; speedup 1.0000x reference)
//
#include <hip/hip_runtime.h>
#include <stdint.h>

typedef __bf16 bf16;
typedef __bf16 bf16x8 __attribute__((ext_vector_type(8)));
typedef float f32x4 __attribute__((ext_vector_type(4)));

#define MFMA16(a, b, c) __builtin_amdgcn_mfma_f32_16x16x32_bf16((a), (b), (c), 0, 0, 0)

// async global->LDS DMA, 16B per lane. LDS dest wave-uniform; HW writes base + lane*16.
__device__ __forceinline__ void ldsdma16(const void* g, void* l) {
  __builtin_amdgcn_global_load_lds((const __attribute__((address_space(1))) void*)g,
                                   (__attribute__((address_space(3))) void*)l, 16, 0, 0);
}

// ---------------------------------------------------------------------------
// prep (merged): z<4 -> transpose-cast W[k][n] fp32 -> WT[n][k] bf16
//                z==4 -> cast x fp32 -> bf16
// ---------------------------------------------------------------------------
__global__ __launch_bounds__(256) void prep_kernel(const float* __restrict__ x,
                                                   const float* __restrict__ Wq,
                                                   const float* __restrict__ Wk,
                                                   const float* __restrict__ Wv,
                                                   const float* __restrict__ Wo,
                                                   bf16* __restrict__ WT,
                                                   bf16* __restrict__ xb) {
  if (blockIdx.z == 4) {
    const int t = (blockIdx.y * 16 + blockIdx.x) * 256 + threadIdx.x;  // 0..65535
#pragma unroll
    for (int it = 0; it < 16; ++it) {
      const int idx = (it * 65536 + t) * 4;
      float4 v = *(const float4*)(x + idx);
      union { bf16 h[4]; uint2 u; } p;
      p.h[0] = (bf16)v.x; p.h[1] = (bf16)v.y; p.h[2] = (bf16)v.z; p.h[3] = (bf16)v.w;
      *(uint2*)(xb + idx) = p.u;
    }
    return;
  }
  __shared__ float tile[64][65];
  const float* src = blockIdx.z == 0 ? Wq : blockIdx.z == 1 ? Wk : blockIdx.z == 2 ? Wv : Wo;
  bf16* dst = WT + (size_t)blockIdx.z * 1024 * 1024;
  const int k0 = blockIdx.y * 64, n0 = blockIdx.x * 64;
  const int rr = threadIdx.x >> 6, c = threadIdx.x & 63;
#pragma unroll
  for (int i = 0; i < 16; ++i) {
    int r = i * 4 + rr;
    tile[r][c] = src[(size_t)(k0 + r) * 1024 + n0 + c];
  }
  __syncthreads();
#pragma unroll
  for (int i = 0; i < 16; ++i) {
    int r = i * 4 + rr;
    dst[(size_t)(n0 + r) * 1024 + k0 + c] = (bf16)tile[c][r];
  }
}

// ---------------------------------------------------------------------------
// QKV GEMM, BK=32 DOUBLE-BUFFERED PREFETCH: one barrier per iter; stage(k+1)
// is issued right after the barrier, so the next barrier's mandatory vmcnt(0)
// drain finds it already in flight for the whole ds_read+MFMA phase.
// xb[4096,1024] @ Wqkv -> QKVc [4096][3072]. sel block-uniform; Q gets
// 0.125*log2(e). 4-chunk rows, swizzle c^((row>>1)&3) (0 conflicts, r1/r2).
// LDS 2*(8+8)=32 KB -> 3 blocks/CU at grid 768.
// ---------------------------------------------------------------------------
__global__ __launch_bounds__(256) void qkv_gemm(const bf16* __restrict__ xb,
                                                const bf16* __restrict__ WT,
                                                const float* __restrict__ bq,
                                                const float* __restrict__ bk,
                                                const float* __restrict__ bv,
                                                bf16* __restrict__ QKVc) {
  __shared__ bf16 As[2][128 * 32] __attribute__((aligned(16)));
  __shared__ bf16 Bs[2][128 * 32] __attribute__((aligned(16)));
  const int tid = threadIdx.x, lane = tid & 63, wave = tid >> 6;
  const int wm = wave >> 1, wn = wave & 1;
  const int quad = lane >> 4, l16 = lane & 15;
  const int m0 = blockIdx.y * 128, n0 = blockIdx.x * 128;

  f32x4 acc[4][4];
  const f32x4 zero = {0.f, 0.f, 0.f, 0.f};
#pragma unroll
  for (int i = 0; i < 4; ++i)
#pragma unroll
    for (int j = 0; j < 4; ++j) acc[i][j] = zero;

  // stage k-tile kk into buffer bu: A 512 chunks + B 512 chunks, 4 DMA/thread
  auto stage = [&](int kk, int bu) {
    const int k0 = kk * 32;
#pragma unroll
    for (int inst = 0; inst < 2; ++inst) {
      int chunk = inst * 256 + tid;           // 0..511
      int row = chunk >> 2;
      int cg = (chunk & 3) ^ ((row >> 1) & 3);
      ldsdma16(xb + (size_t)(m0 + row) * 1024 + k0 + cg * 8,
               (char*)As[bu] + (size_t)(inst * 256 + tid) * 16);
      ldsdma16(WT + (size_t)(n0 + row) * 1024 + k0 + cg * 8,
               (char*)Bs[bu] + (size_t)(inst * 256 + tid) * 16);
    }
  };

  stage(0, 0);
  for (int k = 0; k < 32; ++k) {
    const int bu = k & 1;
    __syncthreads();                 // stage(k) done; buf[bu^1] readers (iter k-1) done
    if (k < 31) stage(k + 1, bu ^ 1);  // prefetch: in flight during frag-read + MFMA
    bf16x8 af[4], bfv[4];
#pragma unroll
    for (int i = 0; i < 4; ++i) {
      int ra = wm * 64 + i * 16 + l16;
      af[i] = ((const bf16x8*)As[bu])[ra * 4 + (quad ^ ((ra >> 1) & 3))];
      int rb = wn * 64 + i * 16 + l16;
      bfv[i] = ((const bf16x8*)Bs[bu])[rb * 4 + (quad ^ ((rb >> 1) & 3))];
    }
#pragma unroll
    for (int i = 0; i < 4; ++i)
#pragma unroll
      for (int j = 0; j < 4; ++j) acc[i][j] = MFMA16(af[i], bfv[j], acc[i][j]);
  }

  const int sel = blockIdx.x >> 3;  // 0:Q 1:K 2:V
  const float* bp = sel == 0 ? bq : sel == 1 ? bk : bv;
  const float scl = (sel == 0) ? 0.18033688f : 1.f;  // 0.125 * log2(e)
#pragma unroll
  for (int j = 0; j < 4; ++j) {
    const int n = n0 + wn * 64 + j * 16 + l16;
    const float bias = bp[n & 1023];
#pragma unroll
    for (int i = 0; i < 4; ++i) {
#pragma unroll
      for (int r = 0; r < 4; ++r) {
        const int token = m0 + wm * 64 + i * 16 + quad * 4 + r;
        QKVc[(size_t)token * 3072 + n] = (bf16)((acc[i][j][r] + bias) * scl);
      }
    }
  }
}

// ---------------------------------------------------------------------------
// V transpose: QKVc[:, 2048:3072] -> Vt[b,h,hd,s]. 64x64 tiles via LDS.
// ---------------------------------------------------------------------------
__global__ __launch_bounds__(256) void v_transpose(const bf16* __restrict__ QKVc,
                                                   bf16* __restrict__ Vt) {
  __shared__ bf16 tile[64][72] __attribute__((aligned(16)));
  const int tid = threadIdx.x;
  const int st = blockIdx.x, h = blockIdx.y, b = blockIdx.z;
  {
    const int t = tid >> 2, cg = (tid & 3) * 16;
    const bf16* src = QKVc + ((size_t)(b * 2048 + st * 64 + t)) * 3072 + 2048 + h * 64 + cg;
    bf16x8 v0 = *(const bf16x8*)src;
    bf16x8 v1 = *(const bf16x8*)(src + 8);
    *(bf16x8*)&tile[t][cg] = v0;
    *(bf16x8*)&tile[t][cg + 8] = v1;
  }
  __syncthreads();
  const int hd = tid & 63, sg = (tid >> 6) * 16;
  bf16 o[16];
#pragma unroll
  for (int i = 0; i < 16; ++i) o[i] = tile[sg + i][hd];
  bf16* dst = Vt + ((size_t)((b * 16 + h) * 64 + hd)) * 2048 + st * 64 + sg;
  *(bf16x8*)dst = *(bf16x8*)&o[0];
  *(bf16x8*)(dst + 8) = *(bf16x8*)&o[8];
}

// ---------------------------------------------------------------------------
// Sliding-window attention (r5, unchanged): DMA-staged + double-buffered K/V.
// 1 block = (b, h, 128-query tile); 4 waves x 32 query rows (2 row-tiles).
// ---------------------------------------------------------------------------
__global__ __launch_bounds__(256) void attn_kernel(const bf16* __restrict__ QKVc,
                                                   const bf16* __restrict__ VtG,
                                                   bf16* __restrict__ Ao) {
  __shared__ bf16 Qs[128 * 64] __attribute__((aligned(16)));     // 16 KB
  __shared__ bf16 Ks[2][64 * 64] __attribute__((aligned(16)));   // 16 KB
  __shared__ bf16 Vs[2][64 * 64] __attribute__((aligned(16)));   // 16 KB
  __shared__ bf16 Ps[4][2][16 * 72] __attribute__((aligned(16)));// 18 KB

  const int tid = threadIdx.x, lane = tid & 63, wave = tid >> 6;
  const int quad = lane >> 4, l16 = lane & 15;
  const int qt = blockIdx.x, h = blockIdx.y, b = blockIdx.z;
  const int q0 = qt * 128;
  const size_t vbase = (size_t)(b * 16 + h) * 131072;  // [HD][S] head base

  // stage Q tile: 1024 chunks, swizzle cc ^ (row&7)
#pragma unroll
  for (int inst = 0; inst < 4; ++inst) {
    int d = inst * 256 + wave * 64 + lane;
    int row = d >> 3, cc = d & 7;
    ldsdma16(QKVc + (size_t)(b * 2048 + q0 + row) * 3072 + h * 64 + ((cc ^ (row & 7)) * 8),
             (char*)Qs + (size_t)(inst * 256 + wave * 64) * 16);
  }

  const int lo = (qt >= 2) ? (2 * qt - 4) : 0;
  const int hi = 2 * qt + 1;

  auto stage_kv = [&](int ck, int bu) {
    const int c0k = ck * 64;
#pragma unroll
    for (int inst = 0; inst < 2; ++inst) {
      int d = inst * 256 + wave * 64 + lane;
      int row = d >> 3, cc = d & 7;
      int sc = (cc ^ (row & 7)) * 8;
      ldsdma16(QKVc + (size_t)(b * 2048 + c0k + row) * 3072 + 1024 + h * 64 + sc,
               (char*)Ks[bu] + (size_t)(inst * 256 + wave * 64) * 16);
      ldsdma16(VtG + vbase + (size_t)row * 2048 + c0k + sc,
               (char*)Vs[bu] + (size_t)(inst * 256 + wave * 64) * 16);
    }
  };

  stage_kv(lo, lo & 1);
  __syncthreads();  // Q + first K/V staged

  bf16x8 qa[2][2];
#pragma unroll
  for (int rt = 0; rt < 2; ++rt) {
    int row = wave * 32 + rt * 16 + l16;
#pragma unroll
    for (int s = 0; s < 2; ++s)
      qa[rt][s] = ((const bf16x8*)Qs)[row * 8 + ((s * 4 + quad) ^ (row & 7))];
  }

  float lrow[2][4];
  f32x4 oacc[2][4];
  const f32x4 zero = {0.f, 0.f, 0.f, 0.f};
#pragma unroll
  for (int rt = 0; rt < 2; ++rt)
#pragma unroll
    for (int r = 0; r < 4; ++r) { lrow[rt][r] = 0.f; oacc[rt][r] = zero; }

  for (int ck = lo; ck <= hi; ++ck) {
    if (ck > lo) __syncthreads();
    if (ck < hi) stage_kv(ck + 1, (ck + 1) & 1);  // prefetch under compute
    const int bu = ck & 1;
    const int c0 = ck * 64;

    bf16x8 kb[4][2], vb[4][2];
#pragma unroll
    for (int nt = 0; nt < 4; ++nt) {
      int rr = nt * 16 + l16;
#pragma unroll
      for (int s = 0; s < 2; ++s) {
        kb[nt][s] = ((const bf16x8*)Ks[bu])[rr * 8 + ((s * 4 + quad) ^ (rr & 7))];
        vb[nt][s] = ((const bf16x8*)Vs[bu])[rr * 8 + ((s * 4 + quad) ^ (rr & 7))];
      }
    }

#pragma unroll
    for (int rt = 0; rt < 2; ++rt) {
      f32x4 sc4[4];
#pragma unroll
      for (int nt = 0; nt < 4; ++nt) {
        f32x4 s = MFMA16(qa[rt][0], kb[nt][0], zero);
        sc4[nt] = MFMA16(qa[rt][1], kb[nt][1], s);
      }

      if (ck >= 2 * qt) {  // diagonal chunks: causal j <= i
#pragma unroll
        for (int r = 0; r < 4; ++r) {
          const int i = q0 + wave * 32 + rt * 16 + quad * 4 + r;
#pragma unroll
          for (int nt = 0; nt < 4; ++nt) {
            const int j = c0 + nt * 16 + l16;
            const float p = (j <= i) ? exp2f(sc4[nt][r]) : 0.f;
            sc4[nt][r] = p;
            lrow[rt][r] += p;
          }
        }
      } else if (ck <= 2 * qt - 3) {  // trailing chunks: window j >= i-255
#pragma unroll
        for (int r = 0; r < 4; ++r) {
          const int i = q0 + wave * 32 + rt * 16 + quad * 4 + r;
#pragma unroll
          for (int nt = 0; nt < 4; ++nt) {
            const int j = c0 + nt * 16 + l16;
            const float p = (j + 255 >= i) ? exp2f(sc4[nt][r]) : 0.f;
            sc4[nt][r] = p;
            lrow[rt][r] += p;
          }
        }
      } else {  // fully valid
#pragma unroll
        for (int r = 0; r < 4; ++r) {
#pragma unroll
          for (int nt = 0; nt < 4; ++nt) {
            const float p = exp2f(sc4[nt][r]);
            sc4[nt][r] = p;
            lrow[rt][r] += p;
          }
        }
      }

#pragma unroll
      for (int nt = 0; nt < 4; ++nt)
#pragma unroll
        for (int r = 0; r < 4; ++r)
          Ps[wave][rt][(quad * 4 + r) * 72 + nt * 16 + l16] = (bf16)sc4[nt][r];
      asm volatile("s_waitcnt lgkmcnt(0)" ::: "memory");  // same-wave LDS RAW
      bf16x8 pa0 = ((const bf16x8*)Ps[wave][rt])[l16 * 9 + quad];
      bf16x8 pa1 = ((const bf16x8*)Ps[wave][rt])[l16 * 9 + 4 + quad];

#pragma unroll
      for (int ht = 0; ht < 4; ++ht) {
        f32x4 o = MFMA16(pa0, vb[ht][0], oacc[rt][ht]);
        oacc[rt][ht] = MFMA16(pa1, vb[ht][1], o);
      }
    }
  }

#pragma unroll
  for (int rt = 0; rt < 2; ++rt) {
#pragma unroll
    for (int r = 0; r < 4; ++r) {
      float lr = lrow[rt][r];
#pragma unroll
      for (int m = 8; m >= 1; m >>= 1) lr += __shfl_xor(lr, m, 64);
      const float inv = 1.f / lr;
      const int row = q0 + wave * 32 + rt * 16 + quad * 4 + r;
      const size_t outb = ((size_t)(b * 2048 + row)) * 1024 + h * 64;
#pragma unroll
      for (int ht = 0; ht < 4; ++ht)
        Ao[outb + ht * 16 + l16] = (bf16)(oacc[rt][ht][r] * inv);
    }
  }
}

// ---------------------------------------------------------------------------
// Output GEMM, BK=32 double-buffered prefetch (same structure as qkv):
// Ao[4096,1024] @ Wo + bo -> fp32. 128x64 tiles, 512 blocks (2/CU), LDS 24 KB.
// ---------------------------------------------------------------------------
__global__ __launch_bounds__(256) void out_gemm(const bf16* __restrict__ Ain,
                                                const bf16* __restrict__ WoT,
                                                const float* __restrict__ bo,
                                                float* __restrict__ out) {
  __shared__ bf16 As[2][128 * 32] __attribute__((aligned(16)));
  __shared__ bf16 Bs[2][64 * 32] __attribute__((aligned(16)));
  const int tid = threadIdx.x, lane = tid & 63, wave = tid >> 6;
  const int wm = wave >> 1, wn = wave & 1;
  const int quad = lane >> 4, l16 = lane & 15;
  const int m0 = blockIdx.y * 128, n0 = blockIdx.x * 64;

  f32x4 acc[4][2];
  const f32x4 zero = {0.f, 0.f, 0.f, 0.f};
#pragma unroll
  for (int i = 0; i < 4; ++i)
#pragma unroll
    for (int j = 0; j < 2; ++j) acc[i][j] = zero;

  auto stage = [&](int kk, int bu) {
    const int k0 = kk * 32;
#pragma unroll
    for (int inst = 0; inst < 2; ++inst) {  // A: 512 chunks
      int chunk = inst * 256 + tid;
      int row = chunk >> 2;
      int cg = (chunk & 3) ^ ((row >> 1) & 3);
      ldsdma16(Ain + (size_t)(m0 + row) * 1024 + k0 + cg * 8,
               (char*)As[bu] + (size_t)(inst * 256 + tid) * 16);
    }
    {  // B: 256 chunks
      int chunk = tid;
      int row = chunk >> 2;
      int cg = (chunk & 3) ^ ((row >> 1) & 3);
      ldsdma16(WoT + (size_t)(n0 + row) * 1024 + k0 + cg * 8,
               (char*)Bs[bu] + (size_t)tid * 16);
    }
  };

  stage(0, 0);
  for (int k = 0; k < 32; ++k) {
    const int bu = k & 1;
    __syncthreads();
    if (k < 31) stage(k + 1, bu ^ 1);
    bf16x8 af[4], bfv[2];
#pragma unroll
    for (int i = 0; i < 4; ++i) {
      int ra = wm * 64 + i * 16 + l16;
      af[i] = ((const bf16x8*)As[bu])[ra * 4 + (quad ^ ((ra >> 1) & 3))];
    }
#pragma unroll
    for (int j = 0; j < 2; ++j) {
      int rb = wn * 32 + j * 16 + l16;
      bfv[j] = ((const bf16x8*)Bs[bu])[rb * 4 + (quad ^ ((rb >> 1) & 3))];
    }
#pragma unroll
    for (int i = 0; i < 4; ++i)
#pragma unroll
      for (int j = 0; j < 2; ++j) acc[i][j] = MFMA16(af[i], bfv[j], acc[i][j]);
  }

#pragma unroll
  for (int j = 0; j < 2; ++j) {
    const int n = n0 + wn * 32 + j * 16 + l16;
    const float bias = bo[n];
#pragma unroll
    for (int i = 0; i < 4; ++i) {
#pragma unroll
      for (int r = 0; r < 4; ++r) {
        const int token = m0 + wm * 64 + i * 16 + quad * 4 + r;
        out[(size_t)token * 1024 + n] = acc[i][j][r] + bias;
      }
    }
  }
}

// ---------------------------------------------------------------------------
extern "C" void kernel_launch(void* const* d_in, const int* in_sizes, int n_in,
                              void* d_out, int out_size, void* d_ws, size_t ws_size,
                              hipStream_t stream) {
  const float* x  = (const float*)d_in[0];
  const float* Wq = (const float*)d_in[1];
  const float* bq = (const float*)d_in[2];
  const float* Wk = (const float*)d_in[3];
  const float* bk = (const float*)d_in[4];
  const float* Wv = (const float*)d_in[5];
  const float* bv = (const float*)d_in[6];
  const float* Wo = (const float*)d_in[7];
  const float* bo = (const float*)d_in[8];
  float* out = (float*)d_out;

  char* ws = (char*)d_ws;
  bf16* xb   = (bf16*)(ws);                      //  8 MB  x bf16
  bf16* WT   = (bf16*)(ws + ((size_t)8 << 20));  //  8 MB  WqT|WkT|WvT|WoT bf16 [n][k]
  bf16* QKVc = (bf16*)(ws + ((size_t)16 << 20)); // 24 MB  [4096][3072] C layout
  bf16* Vt   = (bf16*)(ws + ((size_t)40 << 20)); //  8 MB  [B,H,HD,S]
  bf16* Ao   = (bf16*)(ws + ((size_t)48 << 20)); //  8 MB  [B,S,DIM]

  prep_kernel<<<dim3(16, 16, 5), 256, 0, stream>>>(x, Wq, Wk, Wv, Wo, WT, xb);
  qkv_gemm<<<dim3(24, 32), 256, 0, stream>>>(xb, WT, bq, bk, bv, QKVc);
  v_transpose<<<dim3(32, 16, 2), 256, 0, stream>>>(QKVc, Vt);
  attn_kernel<<<dim3(16, 16, 2), 256, 0, stream>>>(QKVc, Vt, Ao);
  out_gemm<<<dim3(16, 32), 256, 0, stream>>>(Ao, WT + (size_t)3 * 1024 * 1024, bo, out);
}